// Round 9
// baseline (509.258 us; speedup 1.0000x reference)
//
#include <hip/hip_runtime.h>
#include <cmath>

#ifndef M_PI
#define M_PI 3.14159265358979323846
#endif

typedef float v2f __attribute__((ext_vector_type(2)));
typedef float v4f __attribute__((ext_vector_type(4)));

constexpr int Dn = 200;
constexpr int DD = Dn * Dn;        // 40000
constexpr int NC = Dn * Dn * Dn;   // 8,000,000
constexpr int TPR = 25;            // threads per row (8 cells each)
constexpr int RPB = 10;            // rows per block (250 live threads)
constexpr int NBLK = (Dn * Dn) / RPB;  // 4000, divisible by 8 -> bijective XCD swizzle
constexpr float THR = 0.0100001f;  // conservative prefilter (exact test in slow path)

// compile-time component selectors (fold to subregister access under full unroll)
#define C4(v,c) ((c)==0?(v).x:(c)==1?(v).y:(c)==2?(v).z:(v).w)
#define WK(L,A,B,R,k) ((k)==0?(L).x:(k)==1?(L).y: \
                       ((k)>=2&&(k)<=5)?C4(A,(k)-2): \
                       ((k)>=6&&(k)<=9)?C4(B,(k)-6): \
                       ((k)==10?(R).x:(R).y))

__global__ __launch_bounds__(256) void dem_step_kernel(
    const float* __restrict__ gx, const float* __restrict__ gy, const float* __restrict__ gz,
    const float* __restrict__ gvx, const float* __restrict__ gvy, const float* __restrict__ gvz,
    const float* __restrict__ gm, float* __restrict__ out,
    float ETAf, float dtOverPm, float gravTerm)
{
    const int t = threadIdx.x;
    if (t >= TPR * RPB) return;

    const int bid = blockIdx.x;
    const int sb = (bid & 7) * (NBLK / 8) + (bid >> 3);   // XCD-contiguous z-slabs

    const int rowid = sb * RPB + t / TPR;
    const int x0 = (t % TPR) * 8;
    const int zi = rowid / Dn;
    const int yj = rowid % Dn;
    const int cbase = rowid * Dn + x0;
    const int xl = (x0 == 0) ? (Dn - 2) : (x0 - 2);
    const int xr = (x0 == Dn - 8) ? 0 : (x0 + 8);

    // ---- center positions ----
    const v4f Xa = *reinterpret_cast<const v4f*>(gx + cbase);
    const v4f Xb = *reinterpret_cast<const v4f*>(gx + cbase + 4);
    const v4f Ya = *reinterpret_cast<const v4f*>(gy + cbase);
    const v4f Yb = *reinterpret_cast<const v4f*>(gy + cbase + 4);
    const v4f Za = *reinterpret_cast<const v4f*>(gz + cbase);
    const v4f Zb = *reinterpret_cast<const v4f*>(gz + cbase + 4);

    // wrapped y row bases (compile-time indexed after unroll)
    int ybs[5];
    #pragma unroll
    for (int o = 0; o < 5; ++o) {
        int yy = yj + o - 2; yy += (yy < 0) ? Dn : 0; yy -= (yy >= Dn) ? Dn : 0;
        ybs[o] = yy * Dn;
    }

    float fxa[8] = {0,0,0,0,0,0,0,0};
    float fya[8] = {0,0,0,0,0,0,0,0};
    float fza[8] = {0,0,0,0,0,0,0,0};

    for (int i2 = 0; i2 < 5; ++i2) {
        int zz = zi + i2 - 2; zz += (zz < 0) ? Dn : 0; zz -= (zz >= Dn) ? Dn : 0;
        const int zbase = zz * DD;
        const bool zc = (i2 == 2);
        #pragma unroll
        for (int i3 = 0; i3 < 5; ++i3) {
            const int rowb = zbase + ybs[i3];
            const bool ctr = zc && (i3 == 2);     // i3 compile-time; zc uniform

            // xy windows only: f2 + f4 + f4 + f2 per array (z loaded lazily on trigger)
            const v2f wxL = *reinterpret_cast<const v2f*>(gx + rowb + xl);
            const v4f wxA = *reinterpret_cast<const v4f*>(gx + rowb + x0);
            const v4f wxB = *reinterpret_cast<const v4f*>(gx + rowb + x0 + 4);
            const v2f wxR = *reinterpret_cast<const v2f*>(gx + rowb + xr);
            const v2f wyL = *reinterpret_cast<const v2f*>(gy + rowb + xl);
            const v4f wyA = *reinterpret_cast<const v4f*>(gy + rowb + x0);
            const v4f wyB = *reinterpret_cast<const v4f*>(gy + rowb + x0 + 4);
            const v2f wyR = *reinterpret_cast<const v2f*>(gy + rowb + xr);

            // ---- scalar xy screen (sqxy <= sq, so conservative), 4 rotating mins ----
            float mm0 = 1e30f, mm1 = 1e30f, mm2 = 1e30f, mm3 = 1e30f;
            #pragma unroll
            for (int c = 0; c < 8; ++c) {
                const float Xc = (c < 4) ? C4(Xa, c) : C4(Xb, c - 4);
                const float Yc = (c < 4) ? C4(Ya, c) : C4(Yb, c - 4);
                #pragma unroll
                for (int o = 0; o < 5; ++o) {
                    if (o == 2) continue;          // o==2 column handled below
                    const int k = c + o;
                    const float dx = Xc - WK(wxL, wxA, wxB, wxR, k);
                    const float dy = Yc - WK(wyL, wyA, wyB, wyR, k);
                    const float sq = fmaf(dy, dy, dx * dx);
                    const int m = (c + o) & 3;
                    if (m == 0) mm0 = fminf(sq, mm0);
                    else if (m == 1) mm1 = fminf(sq, mm1);
                    else if (m == 2) mm2 = fminf(sq, mm2);
                    else mm3 = fminf(sq, mm3);
                }
            }
            if (!ctr) {   // o==2 column (self-pair on the center row would always trigger)
                #pragma unroll
                for (int c = 0; c < 8; ++c) {
                    const float Xc = (c < 4) ? C4(Xa, c) : C4(Xb, c - 4);
                    const float Yc = (c < 4) ? C4(Ya, c) : C4(Yb, c - 4);
                    const int k = c + 2;
                    const float dx = Xc - WK(wxL, wxA, wxB, wxR, k);
                    const float dy = Yc - WK(wyL, wyA, wyB, wyR, k);
                    const float sq = fmaf(dy, dy, dx * dx);
                    const int m = c & 3;
                    if (m == 0) mm0 = fminf(sq, mm0);
                    else if (m == 1) mm1 = fminf(sq, mm1);
                    else if (m == 2) mm2 = fminf(sq, mm2);
                    else mm3 = fminf(sq, mm3);
                }
            }

            // ---- rare slow path (~1.25%/row): load z window, exact reference math ----
            if (fminf(fminf(mm0, mm1), fminf(mm2, mm3)) < THR) {
                const v2f wzL = *reinterpret_cast<const v2f*>(gz + rowb + xl);
                const v4f wzA = *reinterpret_cast<const v4f*>(gz + rowb + x0);
                const v4f wzB = *reinterpret_cast<const v4f*>(gz + rowb + x0 + 4);
                const v2f wzR = *reinterpret_cast<const v2f*>(gz + rowb + xr);
                #pragma unroll
                for (int c = 0; c < 8; ++c) {
                    const float Xc = (c < 4) ? C4(Xa, c) : C4(Xb, c - 4);
                    const float Yc = (c < 4) ? C4(Ya, c) : C4(Yb, c - 4);
                    const float Zc = (c < 4) ? C4(Za, c) : C4(Zb, c - 4);
                    #pragma unroll
                    for (int o = 0; o < 5; ++o) {
                        const int k = c + o;
                        const float dx = Xc - WK(wxL, wxA, wxB, wxR, k);
                        const float dy = Yc - WK(wyL, wyA, wyB, wyR, k);
                        const float dz = Zc - WK(wzL, wzA, wzB, wzR, k);
                        const float sq = dx*dx + dy*dy + dz*dz;
                        if (sq < THR) {
                            const float dist = sqrtf(sq);
                            if (dist < 0.1f) {
                                const float d = fmaxf(dist, 1e-4f);
                                int nxi = x0 + c + o - 2;
                                nxi += (nxi < 0) ? Dn : 0;
                                nxi -= (nxi >= Dn) ? Dn : 0;
                                const int gi = rowb + nxi;
                                const float dvx = gvx[cbase + c] - gvx[gi];
                                const float dvy = gvy[cbase + c] - gvy[gi];
                                const float dvz = gvz[cbase + c] - gvz[gi];
                                const float vn = (dvx*dx + dvy*dy + dvz*dz) / d;
                                const float coef = 2.0f * (600000.0f*(dist - 0.1f) + ETAf*vn) / d;
                                fxa[c] += coef * dx;
                                fya[c] += coef * dy;
                                fza[c] += coef * dz;
                            }
                        }
                    }
                }
            }
        }
    }

    // ---- velocities + mask loaded only now (frees VGPRs during main loop) ----
    const v4f VXa = *reinterpret_cast<const v4f*>(gvx + cbase);
    const v4f VXb = *reinterpret_cast<const v4f*>(gvx + cbase + 4);
    const v4f VYa = *reinterpret_cast<const v4f*>(gvy + cbase);
    const v4f VYb = *reinterpret_cast<const v4f*>(gvy + cbase + 4);
    const v4f VZa = *reinterpret_cast<const v4f*>(gvz + cbase);
    const v4f VZb = *reinterpret_cast<const v4f*>(gvz + cbase + 4);
    const v4f Ma  = *reinterpret_cast<const v4f*>(gm  + cbase);
    const v4f Mb  = *reinterpret_cast<const v4f*>(gm  + cbase + 4);

    float ox[8], oy[8], oz[8], ovx[8], ovy[8], ovz[8];
    #pragma unroll
    for (int c = 0; c < 8; ++c) {
        const float X = (c < 4) ? C4(Xa, c) : C4(Xb, c - 4);
        const float Y = (c < 4) ? C4(Ya, c) : C4(Yb, c - 4);
        const float Z = (c < 4) ? C4(Za, c) : C4(Zb, c - 4);
        const float VX = (c < 4) ? C4(VXa, c) : C4(VXb, c - 4);
        const float VY = (c < 4) ? C4(VYa, c) : C4(VYb, c - 4);
        const float VZ = (c < 4) ? C4(VZa, c) : C4(VZb, c - 4);
        const float M  = (c < 4) ? C4(Ma,  c) : C4(Mb,  c - 4);

        float fxb = 0.f, fyb = 0.f, fzb = 0.f;
        if (X > 0.1f && X < 0.15f) fxb = 600000.0f * (0.15f - X) - ETAf * VX;
        if (X > 9.9f)              fxb = -600000.0f * (((X - 10.0f) + 0.05f) + 0.05f) - ETAf * VX;
        if (Y > 0.1f && Y < 0.15f) fyb = 600000.0f * (0.15f - Y) - ETAf * VY;
        if (Y > 9.9f)              fyb = -600000.0f * (((Y - 10.0f) + 0.05f) + 0.05f) - ETAf * VY;
        if (Z > 0.1f && Z < 0.15f) fzb = 600000.0f * (0.15f - Z) - ETAf * VZ;
        if (Z > 9.9f)              fzb = -600000.0f * (((Z - 10.0f) + 0.05f) + 0.05f) - ETAf * VZ;

        const float am = dtOverPm * M;
        ovx[c] = VX + am * ((-fxa[c]) + fxb);
        ovy[c] = VY + am * ((-fya[c]) + fyb);
        ovz[c] = VZ + am * ((gravTerm - fza[c]) + fzb);
        ox[c] = X + 1e-4f * ovx[c];
        oy[c] = Y + 1e-4f * ovy[c];
        oz[c] = Z + 1e-4f * ovz[c];
    }

    #define ST(arr, base) \
        __builtin_nontemporal_store((v4f){(arr)[0],(arr)[1],(arr)[2],(arr)[3]}, \
                                    reinterpret_cast<v4f*>(out + (base) + cbase)); \
        __builtin_nontemporal_store((v4f){(arr)[4],(arr)[5],(arr)[6],(arr)[7]}, \
                                    reinterpret_cast<v4f*>(out + (base) + cbase + 4));
    ST(ox,  0L * NC)
    ST(oy,  1L * NC)
    ST(oz,  2L * NC)
    ST(ovx, 3L * NC)
    ST(ovy, 4L * NC)
    ST(ovz, 5L * NC)
    #undef ST
}

extern "C" void kernel_launch(void* const* d_in, const int* in_sizes, int n_in,
                              void* d_out, int out_size, void* d_ws, size_t ws_size,
                              hipStream_t stream) {
    const float* gx  = (const float*)d_in[0];
    const float* gy  = (const float*)d_in[1];
    const float* gz  = (const float*)d_in[2];
    const float* gvx = (const float*)d_in[3];
    const float* gvy = (const float*)d_in[4];
    const float* gvz = (const float*)d_in[5];
    const float* gm  = (const float*)d_in[6];
    float* out = (float*)d_out;

    const double KN  = 600000.0;
    const double PM  = 4.0 / 3.0 * 3.1415 * std::pow(0.05, 3) * 2700.0;
    const double alpha = -std::log(0.5) / M_PI;
    const double gamma = alpha / std::sqrt(alpha * alpha + 1.0);
    const double ETA = 2.0 * gamma * std::sqrt(KN * PM);

    const float ETAf     = (float)ETA;
    const float dtOverPm = (float)(0.0001 / PM);
    const float gravTerm = (float)(-9.8 * PM);

    dem_step_kernel<<<NBLK, 256, 0, stream>>>(gx, gy, gz, gvx, gvy, gvz, gm, out,
                                              ETAf, dtOverPm, gravTerm);
}

// Round 10
// 348.406 us; speedup vs baseline: 1.4617x; 1.4617x over previous
//
#include <hip/hip_runtime.h>
#include <cmath>

#ifndef M_PI
#define M_PI 3.14159265358979323846
#endif

typedef float v2f __attribute__((ext_vector_type(2)));
typedef float v4f __attribute__((ext_vector_type(4)));

constexpr int Dn = 200;
constexpr int DD = Dn * Dn;          // 40000
constexpr int NC = Dn * Dn * Dn;     // 8,000,000
constexpr int TPR = 25;              // threads per row-pair (8 x-cells each)
constexpr int PPB = 10;              // row-pairs per block (250 live threads)
constexpr int NPAIR = Dn * (Dn / 2); // 20000 (z, y-pair) groups
constexpr int NBLK = NPAIR / PPB;    // 2000 blocks, %8==0 -> bijective XCD swizzle
constexpr float THR = 0.0100001f;    // conservative prefilter (exact test in slow path)

// compile-time component selectors (fold to subregister access under full unroll)
#define C4(v,c) ((c)==0?(v).x:(c)==1?(v).y:(c)==2?(v).z:(v).w)
#define WK(L,A,B,R,k) ((k)==0?(L).x:(k)==1?(L).y: \
                       ((k)>=2&&(k)<=5)?C4(A,(k)-2): \
                       ((k)>=6&&(k)<=9)?C4(B,(k)-6): \
                       ((k)==10?(R).x:(R).y))

__global__ __launch_bounds__(256) void dem_step_kernel(
    const float* __restrict__ gx, const float* __restrict__ gy, const float* __restrict__ gz,
    const float* __restrict__ gvx, const float* __restrict__ gvy, const float* __restrict__ gvz,
    const float* __restrict__ gm, float* __restrict__ out,
    float ETAf, float dtOverPm, float gravTerm)
{
    const int t = threadIdx.x;
    if (t >= TPR * PPB) return;

    const int bid = blockIdx.x;
    const int sb = (bid & 7) * (NBLK / 8) + (bid >> 3);   // XCD-contiguous z-slabs

    const int rp = sb * PPB + t / TPR;      // (z, y-pair) index
    const int x0 = (t % TPR) * 8;
    const int zi = rp / (Dn / 2);
    const int y0 = (rp % (Dn / 2)) * 2;     // even base row; cells at y0 and y0+1
    const int cbase0 = (zi * Dn + y0) * Dn + x0;
    const int cbase1 = cbase0 + Dn;
    const int xl = (x0 == 0) ? (Dn - 2) : (x0 - 2);
    const int xr = (x0 == Dn - 8) ? 0 : (x0 + 8);

    // ---- center positions, two cell rows ----
    const v4f Xa0 = *reinterpret_cast<const v4f*>(gx + cbase0);
    const v4f Xb0 = *reinterpret_cast<const v4f*>(gx + cbase0 + 4);
    const v4f Ya0 = *reinterpret_cast<const v4f*>(gy + cbase0);
    const v4f Yb0 = *reinterpret_cast<const v4f*>(gy + cbase0 + 4);
    const v4f Za0 = *reinterpret_cast<const v4f*>(gz + cbase0);
    const v4f Zb0 = *reinterpret_cast<const v4f*>(gz + cbase0 + 4);
    const v4f Xa1 = *reinterpret_cast<const v4f*>(gx + cbase1);
    const v4f Xb1 = *reinterpret_cast<const v4f*>(gx + cbase1 + 4);
    const v4f Ya1 = *reinterpret_cast<const v4f*>(gy + cbase1);
    const v4f Yb1 = *reinterpret_cast<const v4f*>(gy + cbase1 + 4);
    const v4f Za1 = *reinterpret_cast<const v4f*>(gz + cbase1);
    const v4f Zb1 = *reinterpret_cast<const v4f*>(gz + cbase1 + 4);

    // wrapped y row bases for the 6-row union (compile-time indexed after unroll)
    int ybs[6];
    #pragma unroll
    for (int j = 0; j < 6; ++j) {
        int yy = y0 + j - 2; yy += (yy < 0) ? Dn : 0; yy -= (yy >= Dn) ? Dn : 0;
        ybs[j] = yy * Dn;
    }

    float fx0[8] = {0,0,0,0,0,0,0,0}, fy0[8] = {0,0,0,0,0,0,0,0}, fz0[8] = {0,0,0,0,0,0,0,0};
    float fx1[8] = {0,0,0,0,0,0,0,0}, fy1[8] = {0,0,0,0,0,0,0,0}, fz1[8] = {0,0,0,0,0,0,0,0};

    for (int i2 = 0; i2 < 5; ++i2) {
        int zz = zi + i2 - 2; zz += (zz < 0) ? Dn : 0; zz -= (zz >= Dn) ? Dn : 0;
        const int zbase = zz * DD;
        const bool zc = (i2 == 2);
        #pragma unroll
        for (int j = 0; j < 6; ++j) {
            const int rowb = zbase + ybs[j];

            // full 3D windows: f2 + f4 + f4 + f2 per array
            const v2f wxL = *reinterpret_cast<const v2f*>(gx + rowb + xl);
            const v4f wxA = *reinterpret_cast<const v4f*>(gx + rowb + x0);
            const v4f wxB = *reinterpret_cast<const v4f*>(gx + rowb + x0 + 4);
            const v2f wxR = *reinterpret_cast<const v2f*>(gx + rowb + xr);
            const v2f wyL = *reinterpret_cast<const v2f*>(gy + rowb + xl);
            const v4f wyA = *reinterpret_cast<const v4f*>(gy + rowb + x0);
            const v4f wyB = *reinterpret_cast<const v4f*>(gy + rowb + x0 + 4);
            const v2f wyR = *reinterpret_cast<const v2f*>(gy + rowb + xr);
            const v2f wzL = *reinterpret_cast<const v2f*>(gz + rowb + xl);
            const v4f wzA = *reinterpret_cast<const v4f*>(gz + rowb + x0);
            const v4f wzB = *reinterpret_cast<const v4f*>(gz + rowb + x0 + 4);
            const v2f wzR = *reinterpret_cast<const v2f*>(gz + rowb + xr);

            float mm0 = 1e30f, mm1 = 1e30f, mm2 = 1e30f, mm3 = 1e30f;

            // screen one center set against this row; skip2: omit o==2 (self) column
            #define SCREEN(XA,XB,YA,YB,ZA,ZB,skip2) { \
                _Pragma("unroll") \
                for (int c = 0; c < 8; ++c) { \
                    const float Xc = (c < 4) ? C4(XA, c) : C4(XB, c - 4); \
                    const float Yc = (c < 4) ? C4(YA, c) : C4(YB, c - 4); \
                    const float Zc = (c < 4) ? C4(ZA, c) : C4(ZB, c - 4); \
                    _Pragma("unroll") \
                    for (int o = 0; o < 5; ++o) { \
                        if (o == 2) continue; \
                        const int k = c + o; \
                        const float dx = Xc - WK(wxL, wxA, wxB, wxR, k); \
                        const float dy = Yc - WK(wyL, wyA, wyB, wyR, k); \
                        const float dz = Zc - WK(wzL, wzA, wzB, wzR, k); \
                        const float sq = fmaf(dz, dz, fmaf(dy, dy, dx * dx)); \
                        const int m = (c + o) & 3; \
                        if (m == 0) mm0 = fminf(sq, mm0); \
                        else if (m == 1) mm1 = fminf(sq, mm1); \
                        else if (m == 2) mm2 = fminf(sq, mm2); \
                        else mm3 = fminf(sq, mm3); \
                    } \
                } \
                if (!(skip2)) { \
                    _Pragma("unroll") \
                    for (int c = 0; c < 8; ++c) { \
                        const float Xc = (c < 4) ? C4(XA, c) : C4(XB, c - 4); \
                        const float Yc = (c < 4) ? C4(YA, c) : C4(YB, c - 4); \
                        const float Zc = (c < 4) ? C4(ZA, c) : C4(ZB, c - 4); \
                        const int k = c + 2; \
                        const float dx = Xc - WK(wxL, wxA, wxB, wxR, k); \
                        const float dy = Yc - WK(wyL, wyA, wyB, wyR, k); \
                        const float dz = Zc - WK(wzL, wzA, wzB, wzR, k); \
                        const float sq = fmaf(dz, dz, fmaf(dy, dy, dx * dx)); \
                        const int m = c & 3; \
                        if (m == 0) mm0 = fminf(sq, mm0); \
                        else if (m == 1) mm1 = fminf(sq, mm1); \
                        else if (m == 2) mm2 = fminf(sq, mm2); \
                        else mm3 = fminf(sq, mm3); \
                    } \
                } }

            if (j <= 4) SCREEN(Xa0, Xb0, Ya0, Yb0, Za0, Zb0, zc && (j == 2))
            if (j >= 1) SCREEN(Xa1, Xb1, Ya1, Yb1, Za1, Zb1, zc && (j == 3))
            #undef SCREEN

            // ---- rare slow path (~2%/row-window): exact reference math ----
            if (fminf(fminf(mm0, mm1), fminf(mm2, mm3)) < THR) {
                #define SLOW(XA,XB,YA,YB,ZA,ZB,FX,FY,FZ,CB) { \
                    _Pragma("unroll") \
                    for (int c = 0; c < 8; ++c) { \
                        const float Xc = (c < 4) ? C4(XA, c) : C4(XB, c - 4); \
                        const float Yc = (c < 4) ? C4(YA, c) : C4(YB, c - 4); \
                        const float Zc = (c < 4) ? C4(ZA, c) : C4(ZB, c - 4); \
                        _Pragma("unroll") \
                        for (int o = 0; o < 5; ++o) { \
                            const int k = c + o; \
                            const float dx = Xc - WK(wxL, wxA, wxB, wxR, k); \
                            const float dy = Yc - WK(wyL, wyA, wyB, wyR, k); \
                            const float dz = Zc - WK(wzL, wzA, wzB, wzR, k); \
                            const float sq = dx*dx + dy*dy + dz*dz; \
                            if (sq < THR) { \
                                const float dist = sqrtf(sq); \
                                if (dist < 0.1f) { \
                                    const float d = fmaxf(dist, 1e-4f); \
                                    int nxi = x0 + c + o - 2; \
                                    nxi += (nxi < 0) ? Dn : 0; \
                                    nxi -= (nxi >= Dn) ? Dn : 0; \
                                    const int gi = rowb + nxi; \
                                    const float dvx = gvx[(CB) + c] - gvx[gi]; \
                                    const float dvy = gvy[(CB) + c] - gvy[gi]; \
                                    const float dvz = gvz[(CB) + c] - gvz[gi]; \
                                    const float vn = (dvx*dx + dvy*dy + dvz*dz) / d; \
                                    const float coef = 2.0f * (600000.0f*(dist - 0.1f) + ETAf*vn) / d; \
                                    (FX)[c] += coef * dx; \
                                    (FY)[c] += coef * dy; \
                                    (FZ)[c] += coef * dz; \
                                } \
                            } \
                        } \
                    } }
                if (j <= 4) SLOW(Xa0, Xb0, Ya0, Yb0, Za0, Zb0, fx0, fy0, fz0, cbase0)
                if (j >= 1) SLOW(Xa1, Xb1, Ya1, Yb1, Za1, Zb1, fx1, fy1, fz1, cbase1)
                #undef SLOW
            }
        }
    }

    // ---- epilogue: per set, load velocities+mask now, integrate, NT-store ----
    #define FINISH(XA,XB,YA,YB,ZA,ZB,FX,FY,FZ,CB) { \
        const v4f VXa = *reinterpret_cast<const v4f*>(gvx + (CB)); \
        const v4f VXb = *reinterpret_cast<const v4f*>(gvx + (CB) + 4); \
        const v4f VYa = *reinterpret_cast<const v4f*>(gvy + (CB)); \
        const v4f VYb = *reinterpret_cast<const v4f*>(gvy + (CB) + 4); \
        const v4f VZa = *reinterpret_cast<const v4f*>(gvz + (CB)); \
        const v4f VZb = *reinterpret_cast<const v4f*>(gvz + (CB) + 4); \
        const v4f Ma  = *reinterpret_cast<const v4f*>(gm  + (CB)); \
        const v4f Mb  = *reinterpret_cast<const v4f*>(gm  + (CB) + 4); \
        float ox[8], oy[8], oz[8], ovx[8], ovy[8], ovz[8]; \
        _Pragma("unroll") \
        for (int c = 0; c < 8; ++c) { \
            const float X = (c < 4) ? C4(XA, c) : C4(XB, c - 4); \
            const float Y = (c < 4) ? C4(YA, c) : C4(YB, c - 4); \
            const float Z = (c < 4) ? C4(ZA, c) : C4(ZB, c - 4); \
            const float VX = (c < 4) ? C4(VXa, c) : C4(VXb, c - 4); \
            const float VY = (c < 4) ? C4(VYa, c) : C4(VYb, c - 4); \
            const float VZ = (c < 4) ? C4(VZa, c) : C4(VZb, c - 4); \
            const float M  = (c < 4) ? C4(Ma,  c) : C4(Mb,  c - 4); \
            float fxb = 0.f, fyb = 0.f, fzb = 0.f; \
            if (X > 0.1f && X < 0.15f) fxb = 600000.0f * (0.15f - X) - ETAf * VX; \
            if (X > 9.9f)              fxb = -600000.0f * (((X - 10.0f) + 0.05f) + 0.05f) - ETAf * VX; \
            if (Y > 0.1f && Y < 0.15f) fyb = 600000.0f * (0.15f - Y) - ETAf * VY; \
            if (Y > 9.9f)              fyb = -600000.0f * (((Y - 10.0f) + 0.05f) + 0.05f) - ETAf * VY; \
            if (Z > 0.1f && Z < 0.15f) fzb = 600000.0f * (0.15f - Z) - ETAf * VZ; \
            if (Z > 9.9f)              fzb = -600000.0f * (((Z - 10.0f) + 0.05f) + 0.05f) - ETAf * VZ; \
            const float am = dtOverPm * M; \
            ovx[c] = VX + am * ((-(FX)[c]) + fxb); \
            ovy[c] = VY + am * ((-(FY)[c]) + fyb); \
            ovz[c] = VZ + am * ((gravTerm - (FZ)[c]) + fzb); \
            ox[c] = X + 1e-4f * ovx[c]; \
            oy[c] = Y + 1e-4f * ovy[c]; \
            oz[c] = Z + 1e-4f * ovz[c]; \
        } \
        __builtin_nontemporal_store((v4f){ox[0],ox[1],ox[2],ox[3]},   reinterpret_cast<v4f*>(out + 0L*NC + (CB))); \
        __builtin_nontemporal_store((v4f){ox[4],ox[5],ox[6],ox[7]},   reinterpret_cast<v4f*>(out + 0L*NC + (CB) + 4)); \
        __builtin_nontemporal_store((v4f){oy[0],oy[1],oy[2],oy[3]},   reinterpret_cast<v4f*>(out + 1L*NC + (CB))); \
        __builtin_nontemporal_store((v4f){oy[4],oy[5],oy[6],oy[7]},   reinterpret_cast<v4f*>(out + 1L*NC + (CB) + 4)); \
        __builtin_nontemporal_store((v4f){oz[0],oz[1],oz[2],oz[3]},   reinterpret_cast<v4f*>(out + 2L*NC + (CB))); \
        __builtin_nontemporal_store((v4f){oz[4],oz[5],oz[6],oz[7]},   reinterpret_cast<v4f*>(out + 2L*NC + (CB) + 4)); \
        __builtin_nontemporal_store((v4f){ovx[0],ovx[1],ovx[2],ovx[3]}, reinterpret_cast<v4f*>(out + 3L*NC + (CB))); \
        __builtin_nontemporal_store((v4f){ovx[4],ovx[5],ovx[6],ovx[7]}, reinterpret_cast<v4f*>(out + 3L*NC + (CB) + 4)); \
        __builtin_nontemporal_store((v4f){ovy[0],ovy[1],ovy[2],ovy[3]}, reinterpret_cast<v4f*>(out + 4L*NC + (CB))); \
        __builtin_nontemporal_store((v4f){ovy[4],ovy[5],ovy[6],ovy[7]}, reinterpret_cast<v4f*>(out + 4L*NC + (CB) + 4)); \
        __builtin_nontemporal_store((v4f){ovz[0],ovz[1],ovz[2],ovz[3]}, reinterpret_cast<v4f*>(out + 5L*NC + (CB))); \
        __builtin_nontemporal_store((v4f){ovz[4],ovz[5],ovz[6],ovz[7]}, reinterpret_cast<v4f*>(out + 5L*NC + (CB) + 4)); }

    FINISH(Xa0, Xb0, Ya0, Yb0, Za0, Zb0, fx0, fy0, fz0, cbase0)
    FINISH(Xa1, Xb1, Ya1, Yb1, Za1, Zb1, fx1, fy1, fz1, cbase1)
    #undef FINISH
}

extern "C" void kernel_launch(void* const* d_in, const int* in_sizes, int n_in,
                              void* d_out, int out_size, void* d_ws, size_t ws_size,
                              hipStream_t stream) {
    const float* gx  = (const float*)d_in[0];
    const float* gy  = (const float*)d_in[1];
    const float* gz  = (const float*)d_in[2];
    const float* gvx = (const float*)d_in[3];
    const float* gvy = (const float*)d_in[4];
    const float* gvz = (const float*)d_in[5];
    const float* gm  = (const float*)d_in[6];
    float* out = (float*)d_out;

    const double KN  = 600000.0;
    const double PM  = 4.0 / 3.0 * 3.1415 * std::pow(0.05, 3) * 2700.0;
    const double alpha = -std::log(0.5) / M_PI;
    const double gamma = alpha / std::sqrt(alpha * alpha + 1.0);
    const double ETA = 2.0 * gamma * std::sqrt(KN * PM);

    const float ETAf     = (float)ETA;
    const float dtOverPm = (float)(0.0001 / PM);
    const float gravTerm = (float)(-9.8 * PM);

    dem_step_kernel<<<NBLK, 256, 0, stream>>>(gx, gy, gz, gvx, gvy, gvz, gm, out,
                                              ETAf, dtOverPm, gravTerm);
}

// Round 11
// 217.476 us; speedup vs baseline: 2.3417x; 1.6020x over previous
//
#include <hip/hip_runtime.h>
#include <cmath>

#ifndef M_PI
#define M_PI 3.14159265358979323846
#endif

typedef float v2f __attribute__((ext_vector_type(2)));
typedef float v4f __attribute__((ext_vector_type(4)));

constexpr int Dn = 200;
constexpr int DD = Dn * Dn;        // 40000
constexpr int NC = Dn * Dn * Dn;   // 8,000,000
constexpr int TPR = 25;            // threads per row (8 cells each)
constexpr int RPB = 10;            // rows per block (250 live threads)
constexpr int NBLK = (Dn * Dn) / RPB;  // 4000, divisible by 8 -> bijective XCD swizzle
constexpr float THR = 0.0100001f;  // conservative prefilter (exact test in slow path)

// compile-time component selectors (fold to subregister access under full unroll)
#define C4(v,c) ((c)==0?(v).x:(c)==1?(v).y:(c)==2?(v).z:(v).w)
#define WK(L,A,B,R,k) ((k)==0?(L).x:(k)==1?(L).y: \
                       ((k)>=2&&(k)<=5)?C4(A,(k)-2): \
                       ((k)>=6&&(k)<=9)?C4(B,(k)-6): \
                       ((k)==10?(R).x:(R).y))

__global__ __launch_bounds__(256) void dem_step_kernel(
    const float* __restrict__ gx, const float* __restrict__ gy, const float* __restrict__ gz,
    const float* __restrict__ gvx, const float* __restrict__ gvy, const float* __restrict__ gvz,
    const float* __restrict__ gm, float* __restrict__ out,
    float ETAf, float dtOverPm, float gravTerm)
{
    const int t = threadIdx.x;
    if (t >= TPR * RPB) return;

    const int bid = blockIdx.x;
    const int sb = (bid & 7) * (NBLK / 8) + (bid >> 3);   // XCD-contiguous z-slabs

    const int rowid = sb * RPB + t / TPR;
    const int x0 = (t % TPR) * 8;
    const int zi = rowid / Dn;
    const int yj = rowid % Dn;
    const int cbase = rowid * Dn + x0;
    const int xl = (x0 == 0) ? (Dn - 2) : (x0 - 2);
    const int xr = (x0 == Dn - 8) ? 0 : (x0 + 8);

    // ---- center positions ----
    const v4f Xa = *reinterpret_cast<const v4f*>(gx + cbase);
    const v4f Xb = *reinterpret_cast<const v4f*>(gx + cbase + 4);
    const v4f Ya = *reinterpret_cast<const v4f*>(gy + cbase);
    const v4f Yb = *reinterpret_cast<const v4f*>(gy + cbase + 4);
    const v4f Za = *reinterpret_cast<const v4f*>(gz + cbase);
    const v4f Zb = *reinterpret_cast<const v4f*>(gz + cbase + 4);

    // wrapped y row bases (compile-time indexed after unroll)
    int ybs[5];
    #pragma unroll
    for (int o = 0; o < 5; ++o) {
        int yy = yj + o - 2; yy += (yy < 0) ? Dn : 0; yy -= (yy >= Dn) ? Dn : 0;
        ybs[o] = yy * Dn;
    }

    float fxa[8] = {0,0,0,0,0,0,0,0};
    float fya[8] = {0,0,0,0,0,0,0,0};
    float fza[8] = {0,0,0,0,0,0,0,0};

    for (int i2 = 0; i2 < 5; ++i2) {
        int zz = zi + i2 - 2; zz += (zz < 0) ? Dn : 0; zz -= (zz >= Dn) ? Dn : 0;
        const int zbase = zz * DD;
        const bool zc = (i2 == 2);
        #pragma unroll
        for (int i3 = 0; i3 < 5; ++i3) {
            const int rowb = zbase + ybs[i3];
            const bool ctr = zc && (i3 == 2);     // i3 compile-time; zc uniform

            // 12-float windows: f2 + f4 + f4 + f2 per array
            const v2f wxL = *reinterpret_cast<const v2f*>(gx + rowb + xl);
            const v4f wxA = *reinterpret_cast<const v4f*>(gx + rowb + x0);
            const v4f wxB = *reinterpret_cast<const v4f*>(gx + rowb + x0 + 4);
            const v2f wxR = *reinterpret_cast<const v2f*>(gx + rowb + xr);
            const v2f wyL = *reinterpret_cast<const v2f*>(gy + rowb + xl);
            const v4f wyA = *reinterpret_cast<const v4f*>(gy + rowb + x0);
            const v4f wyB = *reinterpret_cast<const v4f*>(gy + rowb + x0 + 4);
            const v2f wyR = *reinterpret_cast<const v2f*>(gy + rowb + xr);
            const v2f wzL = *reinterpret_cast<const v2f*>(gz + rowb + xl);
            const v4f wzA = *reinterpret_cast<const v4f*>(gz + rowb + x0);
            const v4f wzB = *reinterpret_cast<const v4f*>(gz + rowb + x0 + 4);
            const v2f wzR = *reinterpret_cast<const v2f*>(gz + rowb + xr);

            // squared distance for pair (c, offset o), full 3D
            #define SQ(c, o, Xc, Yc, Zc) \
                ({ const int _k = (c) + (o); \
                   const float _dx = (Xc) - WK(wxL, wxA, wxB, wxR, _k); \
                   const float _dy = (Yc) - WK(wyL, wyA, wyB, wyR, _k); \
                   const float _dz = (Zc) - WK(wzL, wzA, wzB, wzR, _k); \
                   fmaf(_dz, _dz, fmaf(_dy, _dy, _dx * _dx)); })

            // ---- screen: min3-friendly accumulators ----
            float mmA = 1e30f, mmB = 1e30f, mmC = 1e30f;
            if (!ctr) {          // 24 of 25 rows: all 5 offsets, no split
                #pragma unroll
                for (int c = 0; c < 8; ++c) {
                    const float Xc = (c < 4) ? C4(Xa, c) : C4(Xb, c - 4);
                    const float Yc = (c < 4) ? C4(Ya, c) : C4(Yb, c - 4);
                    const float Zc = (c < 4) ? C4(Za, c) : C4(Zb, c - 4);
                    const float s0 = SQ(c, 0, Xc, Yc, Zc);
                    const float s1 = SQ(c, 1, Xc, Yc, Zc);
                    const float s2 = SQ(c, 2, Xc, Yc, Zc);
                    const float s3 = SQ(c, 3, Xc, Yc, Zc);
                    const float s4 = SQ(c, 4, Xc, Yc, Zc);
                    mmA = fminf(fminf(s0, s1), mmA);   // -> v_min3_f32
                    mmB = fminf(fminf(s3, s4), mmB);   // -> v_min3_f32
                    mmC = fminf(s2, mmC);
                }
            } else {             // center row: skip o==2 (self-pair)
                #pragma unroll
                for (int c = 0; c < 8; ++c) {
                    const float Xc = (c < 4) ? C4(Xa, c) : C4(Xb, c - 4);
                    const float Yc = (c < 4) ? C4(Ya, c) : C4(Yb, c - 4);
                    const float Zc = (c < 4) ? C4(Za, c) : C4(Zb, c - 4);
                    const float s0 = SQ(c, 0, Xc, Yc, Zc);
                    const float s1 = SQ(c, 1, Xc, Yc, Zc);
                    const float s3 = SQ(c, 3, Xc, Yc, Zc);
                    const float s4 = SQ(c, 4, Xc, Yc, Zc);
                    mmA = fminf(fminf(s0, s1), mmA);
                    mmB = fminf(fminf(s3, s4), mmB);
                }
            }

            // ---- rare slow path: exact reference math for this row ----
            if (fminf(fminf(mmA, mmB), mmC) < THR) {
                #pragma unroll
                for (int c = 0; c < 8; ++c) {
                    const float Xc = (c < 4) ? C4(Xa, c) : C4(Xb, c - 4);
                    const float Yc = (c < 4) ? C4(Ya, c) : C4(Yb, c - 4);
                    const float Zc = (c < 4) ? C4(Za, c) : C4(Zb, c - 4);
                    #pragma unroll
                    for (int o = 0; o < 5; ++o) {
                        const int k = c + o;
                        const float dx = Xc - WK(wxL, wxA, wxB, wxR, k);
                        const float dy = Yc - WK(wyL, wyA, wyB, wyR, k);
                        const float dz = Zc - WK(wzL, wzA, wzB, wzR, k);
                        const float sq = dx*dx + dy*dy + dz*dz;
                        if (sq < THR) {
                            const float dist = sqrtf(sq);
                            if (dist < 0.1f) {
                                const float d = fmaxf(dist, 1e-4f);
                                int nxi = x0 + c + o - 2;
                                nxi += (nxi < 0) ? Dn : 0;
                                nxi -= (nxi >= Dn) ? Dn : 0;
                                const int gi = rowb + nxi;
                                const float dvx = gvx[cbase + c] - gvx[gi];
                                const float dvy = gvy[cbase + c] - gvy[gi];
                                const float dvz = gvz[cbase + c] - gvz[gi];
                                const float vn = (dvx*dx + dvy*dy + dvz*dz) / d;
                                const float coef = 2.0f * (600000.0f*(dist - 0.1f) + ETAf*vn) / d;
                                fxa[c] += coef * dx;
                                fya[c] += coef * dy;
                                fza[c] += coef * dz;
                            }
                        }
                    }
                }
            }
            #undef SQ
        }
    }

    // ---- velocities + mask loaded only now (frees VGPRs during main loop) ----
    const v4f VXa = *reinterpret_cast<const v4f*>(gvx + cbase);
    const v4f VXb = *reinterpret_cast<const v4f*>(gvx + cbase + 4);
    const v4f VYa = *reinterpret_cast<const v4f*>(gvy + cbase);
    const v4f VYb = *reinterpret_cast<const v4f*>(gvy + cbase + 4);
    const v4f VZa = *reinterpret_cast<const v4f*>(gvz + cbase);
    const v4f VZb = *reinterpret_cast<const v4f*>(gvz + cbase + 4);
    const v4f Ma  = *reinterpret_cast<const v4f*>(gm  + cbase);
    const v4f Mb  = *reinterpret_cast<const v4f*>(gm  + cbase + 4);

    float ox[8], oy[8], oz[8], ovx[8], ovy[8], ovz[8];
    #pragma unroll
    for (int c = 0; c < 8; ++c) {
        const float X = (c < 4) ? C4(Xa, c) : C4(Xb, c - 4);
        const float Y = (c < 4) ? C4(Ya, c) : C4(Yb, c - 4);
        const float Z = (c < 4) ? C4(Za, c) : C4(Zb, c - 4);
        const float VX = (c < 4) ? C4(VXa, c) : C4(VXb, c - 4);
        const float VY = (c < 4) ? C4(VYa, c) : C4(VYb, c - 4);
        const float VZ = (c < 4) ? C4(VZa, c) : C4(VZb, c - 4);
        const float M  = (c < 4) ? C4(Ma,  c) : C4(Mb,  c - 4);

        float fxb = 0.f, fyb = 0.f, fzb = 0.f;
        if (X > 0.1f && X < 0.15f) fxb = 600000.0f * (0.15f - X) - ETAf * VX;
        if (X > 9.9f)              fxb = -600000.0f * (((X - 10.0f) + 0.05f) + 0.05f) - ETAf * VX;
        if (Y > 0.1f && Y < 0.15f) fyb = 600000.0f * (0.15f - Y) - ETAf * VY;
        if (Y > 9.9f)              fyb = -600000.0f * (((Y - 10.0f) + 0.05f) + 0.05f) - ETAf * VY;
        if (Z > 0.1f && Z < 0.15f) fzb = 600000.0f * (0.15f - Z) - ETAf * VZ;
        if (Z > 9.9f)              fzb = -600000.0f * (((Z - 10.0f) + 0.05f) + 0.05f) - ETAf * VZ;

        const float am = dtOverPm * M;
        ovx[c] = VX + am * ((-fxa[c]) + fxb);
        ovy[c] = VY + am * ((-fya[c]) + fyb);
        ovz[c] = VZ + am * ((gravTerm - fza[c]) + fzb);
        ox[c] = X + 1e-4f * ovx[c];
        oy[c] = Y + 1e-4f * ovy[c];
        oz[c] = Z + 1e-4f * ovz[c];
    }

    #define ST(arr, base) \
        __builtin_nontemporal_store((v4f){(arr)[0],(arr)[1],(arr)[2],(arr)[3]}, \
                                    reinterpret_cast<v4f*>(out + (base) + cbase)); \
        __builtin_nontemporal_store((v4f){(arr)[4],(arr)[5],(arr)[6],(arr)[7]}, \
                                    reinterpret_cast<v4f*>(out + (base) + cbase + 4));
    ST(ox,  0L * NC)
    ST(oy,  1L * NC)
    ST(oz,  2L * NC)
    ST(ovx, 3L * NC)
    ST(ovy, 4L * NC)
    ST(ovz, 5L * NC)
    #undef ST
}

extern "C" void kernel_launch(void* const* d_in, const int* in_sizes, int n_in,
                              void* d_out, int out_size, void* d_ws, size_t ws_size,
                              hipStream_t stream) {
    const float* gx  = (const float*)d_in[0];
    const float* gy  = (const float*)d_in[1];
    const float* gz  = (const float*)d_in[2];
    const float* gvx = (const float*)d_in[3];
    const float* gvy = (const float*)d_in[4];
    const float* gvz = (const float*)d_in[5];
    const float* gm  = (const float*)d_in[6];
    float* out = (float*)d_out;

    const double KN  = 600000.0;
    const double PM  = 4.0 / 3.0 * 3.1415 * std::pow(0.05, 3) * 2700.0;
    const double alpha = -std::log(0.5) / M_PI;
    const double gamma = alpha / std::sqrt(alpha * alpha + 1.0);
    const double ETA = 2.0 * gamma * std::sqrt(KN * PM);

    const float ETAf     = (float)ETA;
    const float dtOverPm = (float)(0.0001 / PM);
    const float gravTerm = (float)(-9.8 * PM);

    dem_step_kernel<<<NBLK, 256, 0, stream>>>(gx, gy, gz, gvx, gvy, gvz, gm, out,
                                              ETAf, dtOverPm, gravTerm);
}